// Round 16
// baseline (622.871 us; speedup 1.0000x reference)
//
#include <hip/hip_runtime.h>
#include <stdint.h>

typedef __attribute__((ext_vector_type(8))) short bf16x8;
typedef __attribute__((ext_vector_type(4))) float f32x4;
typedef __attribute__((ext_vector_type(4))) int i32x4;
typedef unsigned short u16;

#define GLD_LDS16(g, l) __builtin_amdgcn_global_load_lds( \
    (const __attribute__((address_space(1))) void*)(g),   \
    (__attribute__((address_space(3))) void*)(l), 16, 0, 0)

#define PB() do { __builtin_amdgcn_sched_barrier(0); \
                  __builtin_amdgcn_s_barrier();      \
                  __builtin_amdgcn_sched_barrier(0); } while (0)

#define ACCI(d, a_, b_)  d = __builtin_amdgcn_mfma_i32_16x16x64_i8(a_, b_, d, 0, 0, 0)

#define INV_A (1.0f / 16384.0f)   // act x16,  w x1024
#define INV_P (1.0f / 32768.0f)   // attn x32, w x1024
#define INV_H (1.0f / 65536.0f)   // h x64,    w x1024

__device__ __forceinline__ u16 f2bf(float f) {
  union { float f; uint32_t u; } a; a.f = f;
  uint32_t u = a.u;
  return (u16)((u + 0x7fffu + ((u >> 16) & 1u)) >> 16);
}
__device__ __forceinline__ float bf2f(u16 h) {
  union { uint32_t u; float f; } a; a.u = ((uint32_t)h) << 16;
  return a.f;
}
__device__ __forceinline__ uint32_t q8x4(float a, float b, float c, float d, float s) {
  int qa = (int)rintf(fminf(fmaxf(a * s, -127.f), 127.f));
  int qb = (int)rintf(fminf(fmaxf(b * s, -127.f), 127.f));
  int qc = (int)rintf(fminf(fmaxf(c * s, -127.f), 127.f));
  int qd = (int)rintf(fminf(fmaxf(d * s, -127.f), 127.f));
  return (qa & 255) | ((qb & 255) << 8) | ((qc & 255) << 16) | ((qd & 255) << 24);
}
__device__ __forceinline__ char q8(float v, float s) {
  return (char)(int)rintf(fminf(fmaxf(v * s, -127.f), 127.f));
}

// ---------------- LN1 (shift+window gather, i8 out) + all-weight i8 conversion ----
__global__ __launch_bounds__(256) void ln1_wconv(const float* __restrict__ x,
    const float* __restrict__ gw, const float* __restrict__ bw, char* __restrict__ out,
    const float* __restrict__ qw, const float* __restrict__ pw,
    const float* __restrict__ f1w, const float* __restrict__ f2w,
    char* __restrict__ wb8) {
  int bx = blockIdx.x;
  if (bx >= 16384) {
    int i4 = (bx - 16384) * 1024 + threadIdx.x * 4;
    float w[4];
#pragma unroll
    for (int j = 0; j < 4; j++) {
      int idx = i4 + j;
      if (idx < 786432)        w[j] = qw[idx];
      else if (idx < 1048576)  w[j] = pw[idx - 786432];
      else if (idx < 3145728)  w[j] = f1w[idx - 1048576];
      else                     w[j] = f2w[idx - 3145728];
    }
    *(uint32_t*)(wb8 + i4) = q8x4(w[0], w[1], w[2], w[3], 1024.f);
    return;
  }
  int wid = threadIdx.x >> 6;
  int lane = threadIdx.x & 63;
  int m = (bx << 2) + wid;
  int n = m & 63;
  int bwin = m >> 6;
  int b = bwin >> 8;
  int wi = bwin & 255;
  int h = (((wi >> 4) << 3) + (n >> 3) + 4) & 127;
  int w = (((wi & 15) << 3) + (n & 7) + 4) & 127;
  const float* src = x + (((size_t)((b << 7) + h) << 7) + (size_t)w) * 512;
  int ch = lane << 3;
  float4 v0 = *(const float4*)(src + ch);
  float4 v1 = *(const float4*)(src + ch + 4);
  float vv[8] = {v0.x, v0.y, v0.z, v0.w, v1.x, v1.y, v1.z, v1.w};
  float s = 0.f, s2 = 0.f;
#pragma unroll
  for (int j = 0; j < 8; j++) { s += vv[j]; s2 += vv[j] * vv[j]; }
#pragma unroll
  for (int off = 32; off; off >>= 1) {
    s += __shfl_xor(s, off);
    s2 += __shfl_xor(s2, off);
  }
  float mean = s * (1.f / 512.f);
  float var = s2 * (1.f / 512.f) - mean * mean;
  float rstd = rsqrtf(var + 1e-5f);
  float y[8];
#pragma unroll
  for (int j = 0; j < 8; j++) y[j] = (vv[j] - mean) * rstd * gw[ch + j] + bw[ch + j];
  uint2 o;
  o.x = q8x4(y[0], y[1], y[2], y[3], 16.f);
  o.y = q8x4(y[4], y[5], y[6], y[7], 16.f);
  *(uint2*)(out + ((size_t)m << 9) + ch) = o;
}

// ---------------- i8 128x256-tile GEMM, 2 blocks/CU, K-tile=64B ------------------
// EPI 0: qkv -> bf16 BLOCKED [sel][token][32] (+bias), INV_A
// EPI 2: fc2 -> d_out fp32 = bf2f(sb) + acc*INV_H + bias, ld=512
// EPI 3: fc1 -> SwiGLU (B0=a, B1=gate rows +2048), i8 out x64, ld=2048
template<int EPI, int K>
__global__ __launch_bounds__(512, 4) void gemm2i(
    const char* __restrict__ A, const char* __restrict__ Bw,
    const float* __restrict__ bias, void* __restrict__ outp,
    const float* __restrict__ resid, int NTN) {
  __shared__ __align__(16) char lds[2][3][8192];
  const int NT = K / 64;
  int bid = blockIdx.x;
  int nwg = gridDim.x;
  int wg = (bid & 7) * (nwg >> 3) + (bid >> 3);
  int mt = wg / NTN, nt = wg - mt * NTN;
  int m0 = mt << 7;
  int n0 = (EPI == 3) ? (nt << 7) : (nt << 8);

  int tid = threadIdx.x;
  int wid = tid >> 6, lane = tid & 63;
  int wm = wid >> 2, wn = wid & 3;
  int l15 = lane & 15, lhi = lane >> 4;

  int sr0 = tid >> 2;
  int sc = (tid & 3) ^ ((sr0 >> 1) & 3);
  const char* gA  = A  + (size_t)(m0 + sr0) * K + sc * 16;
  const char* gB0 = Bw + (size_t)(n0 + sr0) * K + sc * 16;
  const char* gB1 = (EPI == 3)
      ? (Bw + (size_t)(2048 + n0 + sr0) * K + sc * 16)
      : (Bw + (size_t)(n0 + 128 + sr0) * K + sc * 16);

  auto stage = [&](int slot, const char* gp, int t) {
    if (t >= NT) return;
    char* ld = &lds[t & 1][slot][0] + tid * 16;
    GLD_LDS16(gp + t * 64, ld);
  };

  int aoff[4], boff[2];
#pragma unroll
  for (int i = 0; i < 4; i++) {
    int r = wm * 64 + i * 16 + l15;
    aoff[i] = r * 64 + ((lhi ^ ((r >> 1) & 3)) << 4);
  }
#pragma unroll
  for (int j = 0; j < 2; j++) {
    int r = wn * 32 + j * 16 + l15;
    boff[j] = r * 64 + ((lhi ^ ((r >> 1) & 3)) << 4);
  }

  i32x4 acc[2][4][2] = {};
  i32x4 afr[4], b0r[2], b1r[2];

  stage(0, gA, 0); stage(1, gB0, 0); stage(2, gB1, 0);
  stage(0, gA, 1); stage(1, gB0, 1);
  asm volatile("s_waitcnt vmcnt(2)" ::: "memory");
  __builtin_amdgcn_sched_barrier(0);
  __builtin_amdgcn_s_barrier();
  __builtin_amdgcn_sched_barrier(0);

  for (int s = 0; s < NT; ++s) {
    const char* Ah  = &lds[s & 1][0][0];
    const char* B0h = &lds[s & 1][1][0];
    const char* B1h = &lds[s & 1][2][0];

#pragma unroll
    for (int i = 0; i < 4; i++) afr[i] = *(const i32x4*)&Ah[aoff[i]];
#pragma unroll
    for (int j = 0; j < 2; j++) b0r[j] = *(const i32x4*)&B0h[boff[j]];
    stage(2, gB1, s + 1);
    PB();
    __builtin_amdgcn_s_setprio(1);
#pragma unroll
    for (int i = 0; i < 4; i++)
#pragma unroll
      for (int j = 0; j < 2; j++) ACCI(acc[0][i][j], afr[i], b0r[j]);
    __builtin_amdgcn_s_setprio(0);
    PB();

#pragma unroll
    for (int j = 0; j < 2; j++) b1r[j] = *(const i32x4*)&B1h[boff[j]];
    stage(0, gA, s + 2);
    stage(1, gB0, s + 2);
    PB();
    __builtin_amdgcn_s_setprio(1);
#pragma unroll
    for (int i = 0; i < 4; i++)
#pragma unroll
      for (int j = 0; j < 2; j++) ACCI(acc[1][i][j], afr[i], b1r[j]);
    __builtin_amdgcn_s_setprio(0);
    if (s >= NT - 2) { asm volatile("s_waitcnt vmcnt(0)" ::: "memory"); }
    else             { asm volatile("s_waitcnt vmcnt(2)" ::: "memory"); }
    __builtin_amdgcn_sched_barrier(0);
    __builtin_amdgcn_s_barrier();
    __builtin_amdgcn_sched_barrier(0);
  }

#pragma unroll
  for (int i = 0; i < 4; i++) {
    int row = m0 + wm * 64 + i * 16 + lhi * 4;
    if (EPI == 0) {
      u16* out = (u16*)outp;
#pragma unroll
      for (int h = 0; h < 2; h++)
#pragma unroll
        for (int j = 0; j < 2; j++) {
          int colb = n0 + h * 128 + wn * 32 + j * 16;
          int col = colb + l15;
          int sh = colb >> 5;
          int d = (colb & 31) + l15;
          float bv = bias[col];
#pragma unroll
          for (int rg = 0; rg < 4; rg++)
            out[(size_t)sh * 2097152 + (size_t)(row + rg) * 32 + d] =
                f2bf((float)acc[h][i][j][rg] * INV_A + bv);
        }
    } else if (EPI == 2) {
      float* out = (float*)outp;
      const u16* sbp = (const u16*)resid;
#pragma unroll
      for (int h = 0; h < 2; h++)
#pragma unroll
        for (int j = 0; j < 2; j++) {
          int col = n0 + h * 128 + wn * 32 + j * 16 + l15;
          float bv = bias[col];
#pragma unroll
          for (int rg = 0; rg < 4; rg++) {
            size_t idx = (size_t)(row + rg) * 512 + col;
            out[idx] = bf2f(sbp[idx]) + (float)acc[h][i][j][rg] * INV_H + bv;
          }
        }
    } else {
      char* out = (char*)outp;
#pragma unroll
      for (int j = 0; j < 2; j++) {
        int col = n0 + wn * 32 + j * 16 + l15;
        float ba_ = bias[col], bg_ = bias[col + 2048];
#pragma unroll
        for (int rg = 0; rg < 4; rg++) {
          float av = (float)acc[0][i][j][rg] * INV_A + ba_;
          float gv = (float)acc[1][i][j][rg] * INV_A + bg_;
          float sw = gv / (1.f + __expf(-gv));
          out[(size_t)(row + rg) * 2048 + col] = q8(sw * av, 64.f);
        }
      }
    }
  }
}

// ---------------- proj GEMM (128x512) fused with residual + LN2 ------------------
// RACE-FIXED schedule: P0 stages B(s+1) (opposite buffer, reads drained at tile s-1
// end barrier); P1 stages A(s+2) (same buffer, A consumed in P0). Gate vmcnt(1)
// drains exactly {A(s+1), B(s+1)x4}. Prologue A0,B0x4,A1 -> vmcnt(1).
__global__ __launch_bounds__(512, 1) void proj_ln2(
    const char* __restrict__ A, const char* __restrict__ Bw,
    const float* __restrict__ pbias, const float* __restrict__ g2,
    const float* __restrict__ b2, const float* __restrict__ xres,
    u16* __restrict__ sbw, char* __restrict__ yb8) {
  __shared__ __align__(16) char lds[2][40960];   // [buf][A 8KB | B 32KB]
  const int K = 512, NT = 8;
  int bid = blockIdx.x;
  int nwg = gridDim.x;
  int wg = (bid & 7) * (nwg >> 3) + (bid >> 3);
  int m0 = wg << 7;

  int tid = threadIdx.x;
  int wid = tid >> 6, lane = tid & 63;
  int wm = wid >> 2, wn = wid & 3;
  int l15 = lane & 15, lhi = lane >> 4;

  int sr0 = tid >> 2;
  int sc = (tid & 3) ^ ((sr0 >> 1) & 3);
  const char* gA = A + (size_t)(m0 + sr0) * K + sc * 16;
  const char* gB[4];
#pragma unroll
  for (int q = 0; q < 4; q++)
    gB[q] = Bw + (size_t)(q * 128 + sr0) * K + sc * 16;

  auto stageA = [&](int t) {
    if (t >= NT) return;
    GLD_LDS16(gA + t * 64, &lds[t & 1][0] + tid * 16);
  };
  auto stageB = [&](int q, int t) {
    if (t >= NT) return;
    GLD_LDS16(gB[q] + t * 64, &lds[t & 1][8192 + q * 8192] + tid * 16);
  };

  int aoff[4], boff[8];
#pragma unroll
  for (int i = 0; i < 4; i++) {
    int r = wm * 64 + i * 16 + l15;
    aoff[i] = r * 64 + ((lhi ^ ((r >> 1) & 3)) << 4);
  }
#pragma unroll
  for (int j = 0; j < 8; j++) {
    int r = wn * 128 + j * 16 + l15;
    boff[j] = 8192 + r * 64 + ((lhi ^ ((r >> 1) & 3)) << 4);
  }

  i32x4 acc[4][8] = {};
  i32x4 afr[4], br[4];

  // prologue: A(0), B(0)x4, A(1); gate keeps A(1) (newest), drains tile0's 5
  stageA(0); stageB(0, 0); stageB(1, 0); stageB(2, 0); stageB(3, 0);
  stageA(1);
  asm volatile("s_waitcnt vmcnt(1)" ::: "memory");
  __builtin_amdgcn_sched_barrier(0);
  __builtin_amdgcn_s_barrier();
  __builtin_amdgcn_sched_barrier(0);

  for (int s = 0; s < NT; ++s) {
    const char* Lh = &lds[s & 1][0];

    // ---- P0: read A(4) + B half1 (4); stage B(s+1)x4 (opposite buffer)
#pragma unroll
    for (int i = 0; i < 4; i++) afr[i] = *(const i32x4*)&Lh[aoff[i]];
#pragma unroll
    for (int j = 0; j < 4; j++) br[j] = *(const i32x4*)&Lh[boff[j]];
    stageB(0, s + 1); stageB(1, s + 1); stageB(2, s + 1); stageB(3, s + 1);
    PB();
    __builtin_amdgcn_s_setprio(1);
#pragma unroll
    for (int i = 0; i < 4; i++)
#pragma unroll
      for (int j = 0; j < 4; j++) ACCI(acc[i][j], afr[i], br[j]);
    __builtin_amdgcn_s_setprio(0);
    PB();

    // ---- P1: read B half2 (4); stage A(s+2) (same buffer, A consumed in P0)
#pragma unroll
    for (int j = 0; j < 4; j++) br[j] = *(const i32x4*)&Lh[boff[4 + j]];
    stageA(s + 2);
    PB();
    __builtin_amdgcn_s_setprio(1);
#pragma unroll
    for (int i = 0; i < 4; i++)
#pragma unroll
      for (int j = 0; j < 4; j++) ACCI(acc[i][4 + j], afr[i], br[j]);
    __builtin_amdgcn_s_setprio(0);
    // gate: drain {A(s+1), B(s+1)x4}; keep A(s+2)
    if (s >= NT - 2) { asm volatile("s_waitcnt vmcnt(0)" ::: "memory"); }
    else             { asm volatile("s_waitcnt vmcnt(1)" ::: "memory"); }
    __builtin_amdgcn_sched_barrier(0);
    __builtin_amdgcn_s_barrier();
    __builtin_amdgcn_sched_barrier(0);
  }

  // ---------------- epilogue: s = x + acc*INV_P + bias; LN2 -> yb8 ---------------
  float pb_[8], gv_[8], bv_[8];
#pragma unroll
  for (int j = 0; j < 8; j++) {
    int col = wn * 128 + j * 16 + l15;
    pb_[j] = pbias[col];
    gv_[j] = g2[col];
    bv_[j] = b2[col];
  }
  size_t pix[4][4];
  float s1[4][4], s2_[4][4];
#pragma unroll
  for (int i = 0; i < 4; i++)
#pragma unroll
    for (int rg = 0; rg < 4; rg++) {
      int m = m0 + wm * 64 + i * 16 + lhi * 4 + rg;
      int b = m >> 14, wi2 = (m >> 6) & 255, n = m & 63;
      int hh = (((wi2 >> 4) << 3) + (n >> 3) + 4) & 127;
      int w = (((wi2 & 15) << 3) + (n & 7) + 4) & 127;
      pix[i][rg] = (((size_t)((b << 7) + hh) << 7) + (size_t)w) << 9;
      float a1 = 0.f, a2 = 0.f;
#pragma unroll
      for (int j = 0; j < 8; j++) {
        int col = wn * 128 + j * 16 + l15;
        float sv = xres[pix[i][rg] + col] + (float)acc[i][j][rg] * INV_P + pb_[j];
        sbw[pix[i][rg] + col] = f2bf(sv);
        acc[i][j][rg] = __float_as_int(sv);
        a1 += sv; a2 += sv * sv;
      }
      s1[i][rg] = a1; s2_[i][rg] = a2;
    }
#pragma unroll
  for (int i = 0; i < 4; i++)
#pragma unroll
    for (int rg = 0; rg < 4; rg++) {
#pragma unroll
      for (int off = 1; off < 16; off <<= 1) {
        s1[i][rg] += __shfl_xor(s1[i][rg], off);
        s2_[i][rg] += __shfl_xor(s2_[i][rg], off);
      }
    }
  float* st = (float*)lds;
  __syncthreads();
  if (l15 == 0) {
#pragma unroll
    for (int i = 0; i < 4; i++)
#pragma unroll
      for (int rg = 0; rg < 4; rg++) {
        int lrow = wm * 64 + i * 16 + lhi * 4 + rg;
        st[(lrow * 4 + wn) * 2]     = s1[i][rg];
        st[(lrow * 4 + wn) * 2 + 1] = s2_[i][rg];
      }
  }
  __syncthreads();
#pragma unroll
  for (int i = 0; i < 4; i++)
#pragma unroll
    for (int rg = 0; rg < 4; rg++) {
      int lrow = wm * 64 + i * 16 + lhi * 4 + rg;
      float m1 = 0.f, m2 = 0.f;
#pragma unroll
      for (int w4 = 0; w4 < 4; w4++) {
        m1 += st[(lrow * 4 + w4) * 2];
        m2 += st[(lrow * 4 + w4) * 2 + 1];
      }
      float mean = m1 * (1.f / 512.f);
      float var = m2 * (1.f / 512.f) - mean * mean;
      float rstd = rsqrtf(var + 1e-5f);
#pragma unroll
      for (int j = 0; j < 8; j++) {
        int col = wn * 128 + j * 16 + l15;
        float y = (__int_as_float(acc[i][j][rg]) - mean) * rstd * gv_[j] + bv_[j];
        yb8[pix[i][rg] + col] = q8(y, 16.f);
      }
    }
}

// ---------------- MFMA windowed attention (blocked bf16 qkv in, i8 out x32) -------
__global__ __launch_bounds__(256) void attn_mfma(
    const u16* __restrict__ qkv, char* __restrict__ out) {
  __shared__ __align__(16) char alds[4][15360];
  int tid = threadIdx.x;
  int wid = tid >> 6, lane = tid & 63;
  int bwin = blockIdx.x >> 2;
  int head = ((blockIdx.x & 3) << 2) + wid;
  int wi = bwin & 255;
  int wr = wi >> 4, wc = wi & 15;
  char* Wb = alds[wid];
  u16* Qr = (u16*)Wb;
  u16* Kr = (u16*)(Wb + 5120);
  u16* Vt = (u16*)(Wb + 10240);
  u16* PT = (u16*)Wb;
  int t = lane;
  int l15 = lane & 15, lhi = lane >> 4;
  size_t tok = (size_t)(bwin << 6) + t;
  const u16* qb = qkv + (size_t)head * 2097152 + tok * 32;
  union U { uint4 u; u16 s[8]; };
  U vq[4], vk[4], vv[4];
#pragma unroll
  for (int g = 0; g < 4; g++) {
    vq[g].u = *(const uint4*)(qb + (g << 3));
    vk[g].u = *(const uint4*)(qb + 33554432 + (g << 3));
    vv[g].u = *(const uint4*)(qb + 67108864 + (g << 3));
  }
  float q[32], k[32];
#pragma unroll
  for (int j = 0; j < 32; j++) {
    q[j] = bf2f(vq[j >> 3].s[j & 7]);
    k[j] = bf2f(vk[j >> 3].s[j & 7]);
  }
  int r = t >> 3, c = t & 7;
#pragma unroll
  for (int d = 0; d < 16; d++) {
    float pos = (d < 8) ? (float)r : (float)c;
    int dd = (d < 8) ? d : d - 8;
    float ang = pos * __expf(-(float)dd * 1.1512925465f);
    float sn, cs;
    __sincosf(ang, &sn, &cs);
    float q1 = q[d], q2 = q[d + 16];
    q[d] = q1 * cs - q2 * sn;  q[d + 16] = q2 * cs + q1 * sn;
    float k1 = k[d], k2 = k[d + 16];
    k[d] = k1 * cs - k2 * sn;  k[d + 16] = k2 * cs + k1 * sn;
  }
#pragma unroll
  for (int j = 0; j < 32; j++) q[j] *= 0.17677669529663687f;
#pragma unroll
  for (int sl = 0; sl < 4; sl++) {
    U tq, tk;
#pragma unroll
    for (int j = 0; j < 8; j++) { tq.s[j] = f2bf(q[sl * 8 + j]); tk.s[j] = f2bf(k[sl * 8 + j]); }
    *(uint4*)(Qr + t * 40 + sl * 8) = tq.u;
    *(uint4*)(Kr + t * 40 + sl * 8) = tk.u;
  }
#pragma unroll
  for (int j = 0; j < 32; j++) Vt[j * 72 + t] = vv[j >> 3].s[j & 7];
  bf16x8 kf[4], qf[4];
#pragma unroll
  for (int i = 0; i < 4; i++) {
    kf[i] = *(const bf16x8*)(Kr + (i * 16 + l15) * 40 + lhi * 8);
    qf[i] = *(const bf16x8*)(Qr + (i * 16 + l15) * 40 + lhi * 8);
  }
  f32x4 zz = {0.f, 0.f, 0.f, 0.f};
  f32x4 st[4][4];
#pragma unroll
  for (int mi = 0; mi < 4; mi++)
#pragma unroll
    for (int nj = 0; nj < 4; nj++)
      st[mi][nj] = __builtin_amdgcn_mfma_f32_16x16x32_bf16(kf[mi], qf[nj], zz, 0, 0, 0);
  if (wr == 15 || wc == 15) {
    int idh = (wr == 15) ? ((r >= 4) ? 2 : 1) : 0;
    int idw = (wc == 15) ? ((c >= 4) ? 2 : 1) : 0;
    int code = idh * 3 + idw;
    int cq[4], cm[4][4];
#pragma unroll
    for (int nj = 0; nj < 4; nj++) cq[nj] = __shfl(code, nj * 16 + l15);
#pragma unroll
    for (int mi = 0; mi < 4; mi++)
#pragma unroll
      for (int rg = 0; rg < 4; rg++) cm[mi][rg] = __shfl(code, mi * 16 + lhi * 4 + rg);
#pragma unroll
    for (int mi = 0; mi < 4; mi++)
#pragma unroll
      for (int nj = 0; nj < 4; nj++)
#pragma unroll
        for (int rg = 0; rg < 4; rg++)
          if (cm[mi][rg] != cq[nj]) st[mi][nj][rg] -= 100.f;
  }
  float inv_[4];
#pragma unroll
  for (int nj = 0; nj < 4; nj++) {
    float mx = -1e30f;
#pragma unroll
    for (int mi = 0; mi < 4; mi++)
#pragma unroll
      for (int rg = 0; rg < 4; rg++) mx = fmaxf(mx, st[mi][nj][rg]);
    mx = fmaxf(mx, __shfl_xor(mx, 16));
    mx = fmaxf(mx, __shfl_xor(mx, 32));
    float sum = 0.f;
#pragma unroll
    for (int mi = 0; mi < 4; mi++)
#pragma unroll
      for (int rg = 0; rg < 4; rg++) {
        float p = __expf(st[mi][nj][rg] - mx);
        st[mi][nj][rg] = p;
        sum += p;
      }
    sum += __shfl_xor(sum, 16);
    sum += __shfl_xor(sum, 32);
    inv_[nj] = 1.f / sum;
  }
#pragma unroll
  for (int mi = 0; mi < 4; mi++)
#pragma unroll
    for (int nj = 0; nj < 4; nj++) {
      uint32_t lo, hi;
      asm("v_cvt_pk_bf16_f32 %0, %1, %2" : "=v"(lo) : "v"(st[mi][nj][0]), "v"(st[mi][nj][1]));
      asm("v_cvt_pk_bf16_f32 %0, %1, %2" : "=v"(hi) : "v"(st[mi][nj][2]), "v"(st[mi][nj][3]));
      uint2 pr; pr.x = lo; pr.y = hi;
      *(uint2*)(PT + (nj * 16 + l15) * 72 + mi * 16 + lhi * 4) = pr;
    }
  bf16x8 vf[2][2], pf[4][2];
#pragma unroll
  for (int i = 0; i < 2; i++)
#pragma unroll
    for (int kc = 0; kc < 2; kc++)
      vf[i][kc] = *(const bf16x8*)(Vt + (i * 16 + l15) * 72 + kc * 32 + lhi * 8);
#pragma unroll
  for (int nj = 0; nj < 4; nj++)
#pragma unroll
    for (int kc = 0; kc < 2; kc++)
      pf[nj][kc] = *(const bf16x8*)(PT + (nj * 16 + l15) * 72 + kc * 32 + lhi * 8);
  char* Ot = Wb;
#pragma unroll
  for (int i = 0; i < 2; i++)
#pragma unroll
    for (int nj = 0; nj < 4; nj++) {
      f32x4 o = __builtin_amdgcn_mfma_f32_16x16x32_bf16(vf[i][0], pf[nj][0], zz, 0, 0, 0);
      o = __builtin_amdgcn_mfma_f32_16x16x32_bf16(vf[i][1], pf[nj][1], o, 0, 0, 0);
      float iv32 = inv_[nj] * 32.f;
      uint32_t pk = q8x4(o[0] * iv32, o[1] * iv32, o[2] * iv32, o[3] * iv32, 1.f);
      *(uint32_t*)(Ot + (nj * 16 + l15) * 40 + i * 16 + lhi * 4) = pk;
    }
#pragma unroll
  for (int g = 0; g < 4; g++) {
    int tl = g * 16 + (lane >> 2);
    int ch_ = (lane & 3) << 3;
    uint2 v = *(const uint2*)(Ot + tl * 40 + ch_);
    *(uint2*)(out + (size_t)((bwin << 6) + tl) * 512 + (head << 5) + ch_) = v;
  }
}

// ---------------- launch ----------------
extern "C" void kernel_launch(void* const* d_in, const int* in_sizes, int n_in,
                              void* d_out, int out_size, void* d_ws, size_t ws_size,
                              hipStream_t stream) {
  (void)in_sizes; (void)n_in; (void)out_size; (void)ws_size;
  const float* x      = (const float*)d_in[0];
  const float* n1g    = (const float*)d_in[2];
  const float* n1b    = (const float*)d_in[3];
  const float* qkv_w  = (const float*)d_in[4];
  const float* qkv_b  = (const float*)d_in[5];
  const float* proj_w = (const float*)d_in[6];
  const float* proj_b = (const float*)d_in[7];
  const float* n2g    = (const float*)d_in[8];
  const float* n2b    = (const float*)d_in[9];
  const float* fc1_w  = (const float*)d_in[10];
  const float* fc1_b  = (const float*)d_in[11];
  const float* fc2_w  = (const float*)d_in[12];
  const float* fc2_b  = (const float*)d_in[13];

  const size_t MB = 1048576ULL;
  char* ws = (char*)d_ws;
  char* wb8  = ws;                        // [0,4MB): qkv|proj|fc1|fc2 i8 weights
  char* wq8  = wb8;
  char* wp8  = wb8 + 786432;
  char* wf18 = wb8 + 1048576;
  char* wf28 = wb8 + 3145728;
  char* xw8  = ws + 8 * MB;               // [8,40): LN1 i8; later attn8
  char* attn8 = xw8;
  u16*  qkvb = (u16*)(ws + 72 * MB);      // [72,264): blocked bf16 qkv
  char* hb8  = ws + 8 * MB;               // [8,136): fc1 i8 h (qkv/attn dead)
  u16*  sb   = (u16*)(ws + 264 * MB);     // [264,328): bf16 residual s
  char* yb8  = ws + 328 * MB;             // [328,360): LN2 i8 out

  ln1_wconv<<<20480, 256, 0, stream>>>(x, n1g, n1b, xw8,
                                       qkv_w, proj_w, fc1_w, fc2_w, wb8);
  gemm2i<0, 512><<<3072, 512, 0, stream>>>(xw8, wq8, qkv_b, qkvb, nullptr, 6);
  attn_mfma<<<4096, 256, 0, stream>>>(qkvb, attn8);
  proj_ln2<<<512, 512, 0, stream>>>(attn8, wp8, proj_b, n2g, n2b, x, sb, yb8);
  gemm2i<3, 512><<<8192, 512, 0, stream>>>(yb8, wf18, fc1_b, hb8, nullptr, 16);
  gemm2i<2, 2048><<<1024, 512, 0, stream>>>(hb8, wf28, fc2_b, d_out,
                                            (const float*)sb, 2);
}

// Round 17
// 563.939 us; speedup vs baseline: 1.1045x; 1.1045x over previous
//
#include <hip/hip_runtime.h>
#include <stdint.h>

typedef __attribute__((ext_vector_type(8))) short bf16x8;
typedef __attribute__((ext_vector_type(4))) float f32x4;
typedef __attribute__((ext_vector_type(4))) int i32x4;
typedef unsigned short u16;

#define GLD_LDS16(g, l) __builtin_amdgcn_global_load_lds( \
    (const __attribute__((address_space(1))) void*)(g),   \
    (__attribute__((address_space(3))) void*)(l), 16, 0, 0)

#define PB() do { __builtin_amdgcn_sched_barrier(0); \
                  __builtin_amdgcn_s_barrier();      \
                  __builtin_amdgcn_sched_barrier(0); } while (0)

#define ACCI(d, a_, b_)  d = __builtin_amdgcn_mfma_i32_16x16x64_i8(a_, b_, d, 0, 0, 0)

#define INV_A (1.0f / 16384.0f)   // act x16,  w x1024
#define INV_P (1.0f / 32768.0f)   // attn x32, w x1024
#define INV_H (1.0f / 65536.0f)   // h x64,    w x1024

__device__ __forceinline__ u16 f2bf(float f) {
  union { float f; uint32_t u; } a; a.f = f;
  uint32_t u = a.u;
  return (u16)((u + 0x7fffu + ((u >> 16) & 1u)) >> 16);
}
__device__ __forceinline__ float bf2f(u16 h) {
  union { uint32_t u; float f; } a; a.u = ((uint32_t)h) << 16;
  return a.f;
}
__device__ __forceinline__ uint32_t q8x4(float a, float b, float c, float d, float s) {
  int qa = (int)rintf(fminf(fmaxf(a * s, -127.f), 127.f));
  int qb = (int)rintf(fminf(fmaxf(b * s, -127.f), 127.f));
  int qc = (int)rintf(fminf(fmaxf(c * s, -127.f), 127.f));
  int qd = (int)rintf(fminf(fmaxf(d * s, -127.f), 127.f));
  return (qa & 255) | ((qb & 255) << 8) | ((qc & 255) << 16) | ((qd & 255) << 24);
}
__device__ __forceinline__ char q8(float v, float s) {
  return (char)(int)rintf(fminf(fmaxf(v * s, -127.f), 127.f));
}

// ---------------- LN1 (shift+window gather, i8 out) + all-weight i8 conversion ----
__global__ __launch_bounds__(256) void ln1_wconv(const float* __restrict__ x,
    const float* __restrict__ gw, const float* __restrict__ bw, char* __restrict__ out,
    const float* __restrict__ qw, const float* __restrict__ pw,
    const float* __restrict__ f1w, const float* __restrict__ f2w,
    char* __restrict__ wb8) {
  int bx = blockIdx.x;
  if (bx >= 16384) {
    int i4 = (bx - 16384) * 1024 + threadIdx.x * 4;
    float w[4];
#pragma unroll
    for (int j = 0; j < 4; j++) {
      int idx = i4 + j;
      if (idx < 786432)        w[j] = qw[idx];
      else if (idx < 1048576)  w[j] = pw[idx - 786432];
      else if (idx < 3145728)  w[j] = f1w[idx - 1048576];
      else                     w[j] = f2w[idx - 3145728];
    }
    *(uint32_t*)(wb8 + i4) = q8x4(w[0], w[1], w[2], w[3], 1024.f);
    return;
  }
  int wid = threadIdx.x >> 6;
  int lane = threadIdx.x & 63;
  int m = (bx << 2) + wid;
  int n = m & 63;
  int bwin = m >> 6;
  int b = bwin >> 8;
  int wi = bwin & 255;
  int h = (((wi >> 4) << 3) + (n >> 3) + 4) & 127;
  int w = (((wi & 15) << 3) + (n & 7) + 4) & 127;
  const float* src = x + (((size_t)((b << 7) + h) << 7) + (size_t)w) * 512;
  int ch = lane << 3;
  float4 v0 = *(const float4*)(src + ch);
  float4 v1 = *(const float4*)(src + ch + 4);
  float vv[8] = {v0.x, v0.y, v0.z, v0.w, v1.x, v1.y, v1.z, v1.w};
  float s = 0.f, s2 = 0.f;
#pragma unroll
  for (int j = 0; j < 8; j++) { s += vv[j]; s2 += vv[j] * vv[j]; }
#pragma unroll
  for (int off = 32; off; off >>= 1) {
    s += __shfl_xor(s, off);
    s2 += __shfl_xor(s2, off);
  }
  float mean = s * (1.f / 512.f);
  float var = s2 * (1.f / 512.f) - mean * mean;
  float rstd = rsqrtf(var + 1e-5f);
  float y[8];
#pragma unroll
  for (int j = 0; j < 8; j++) y[j] = (vv[j] - mean) * rstd * gw[ch + j] + bw[ch + j];
  uint2 o;
  o.x = q8x4(y[0], y[1], y[2], y[3], 16.f);
  o.y = q8x4(y[4], y[5], y[6], y[7], 16.f);
  *(uint2*)(out + ((size_t)m << 9) + ch) = o;
}

// ---------------- LN2: bf16 residual in -> i8 out ----------------
__global__ __launch_bounds__(256) void ln2_q8(const u16* __restrict__ sb,
    const float* __restrict__ gw, const float* __restrict__ bw,
    char* __restrict__ out) {
  int wid = threadIdx.x >> 6;
  int lane = threadIdx.x & 63;
  int m = (blockIdx.x << 2) + wid;
  int ch = lane << 3;
  union { uint4 u; u16 hh[8]; } in;
  in.u = *(const uint4*)(sb + ((size_t)m << 9) + ch);
  float vv[8];
#pragma unroll
  for (int j = 0; j < 8; j++) vv[j] = bf2f(in.hh[j]);
  float s = 0.f, s2 = 0.f;
#pragma unroll
  for (int j = 0; j < 8; j++) { s += vv[j]; s2 += vv[j] * vv[j]; }
#pragma unroll
  for (int off = 32; off; off >>= 1) {
    s += __shfl_xor(s, off);
    s2 += __shfl_xor(s2, off);
  }
  float mean = s * (1.f / 512.f);
  float var = s2 * (1.f / 512.f) - mean * mean;
  float rstd = rsqrtf(var + 1e-5f);
  float y[8];
#pragma unroll
  for (int j = 0; j < 8; j++) y[j] = (vv[j] - mean) * rstd * gw[ch + j] + bw[ch + j];
  uint2 o;
  o.x = q8x4(y[0], y[1], y[2], y[3], 16.f);
  o.y = q8x4(y[4], y[5], y[6], y[7], 16.f);
  *(uint2*)(out + ((size_t)m << 9) + ch) = o;
}

// ---------------- i8 128x256-tile GEMM, 2 blocks/CU, K-tile=64B ------------------
// EPI 0: qkv -> bf16 BLOCKED [sel][token][32] (+bias), INV_A
// EPI 1: proj -> bf16 s = x + acc*INV_P + bias (window-reverse scatter)
// EPI 2: fc2 -> d_out fp32 = bf2f(sb) + acc*INV_H + bias, ld=512
// EPI 3: fc1 -> SwiGLU (B0=a, B1=gate rows +2048), i8 out x64, ld=2048
template<int EPI, int K>
__global__ __launch_bounds__(512, 4) void gemm2i(
    const char* __restrict__ A, const char* __restrict__ Bw,
    const float* __restrict__ bias, void* __restrict__ outp,
    const float* __restrict__ resid, int NTN) {
  __shared__ __align__(16) char lds[2][3][8192];
  const int NT = K / 64;
  int bid = blockIdx.x;
  int nwg = gridDim.x;
  int wg = (bid & 7) * (nwg >> 3) + (bid >> 3);   // bijective XCD swizzle (nwg%8==0)
  int mt = wg / NTN, nt = wg - mt * NTN;
  int m0 = mt << 7;
  int n0 = (EPI == 3) ? (nt << 7) : (nt << 8);

  int tid = threadIdx.x;
  int wid = tid >> 6, lane = tid & 63;
  int wm = wid >> 2, wn = wid & 3;
  int l15 = lane & 15, lhi = lane >> 4;

  int sr0 = tid >> 2;
  int sc = (tid & 3) ^ ((sr0 >> 1) & 3);
  const char* gA  = A  + (size_t)(m0 + sr0) * K + sc * 16;
  const char* gB0 = Bw + (size_t)(n0 + sr0) * K + sc * 16;
  const char* gB1 = (EPI == 3)
      ? (Bw + (size_t)(2048 + n0 + sr0) * K + sc * 16)
      : (Bw + (size_t)(n0 + 128 + sr0) * K + sc * 16);

  auto stage = [&](int slot, const char* gp, int t) {
    if (t >= NT) return;
    char* ld = &lds[t & 1][slot][0] + tid * 16;
    GLD_LDS16(gp + t * 64, ld);
  };

  int aoff[4], boff[2];
#pragma unroll
  for (int i = 0; i < 4; i++) {
    int r = wm * 64 + i * 16 + l15;
    aoff[i] = r * 64 + ((lhi ^ ((r >> 1) & 3)) << 4);
  }
#pragma unroll
  for (int j = 0; j < 2; j++) {
    int r = wn * 32 + j * 16 + l15;
    boff[j] = r * 64 + ((lhi ^ ((r >> 1) & 3)) << 4);
  }

  i32x4 acc[2][4][2] = {};
  i32x4 afr[4], b0r[2], b1r[2];

  stage(0, gA, 0); stage(1, gB0, 0); stage(2, gB1, 0);
  stage(0, gA, 1); stage(1, gB0, 1);
  asm volatile("s_waitcnt vmcnt(2)" ::: "memory");
  __builtin_amdgcn_sched_barrier(0);
  __builtin_amdgcn_s_barrier();
  __builtin_amdgcn_sched_barrier(0);

  for (int s = 0; s < NT; ++s) {
    const char* Ah  = &lds[s & 1][0][0];
    const char* B0h = &lds[s & 1][1][0];
    const char* B1h = &lds[s & 1][2][0];

#pragma unroll
    for (int i = 0; i < 4; i++) afr[i] = *(const i32x4*)&Ah[aoff[i]];
#pragma unroll
    for (int j = 0; j < 2; j++) b0r[j] = *(const i32x4*)&B0h[boff[j]];
    stage(2, gB1, s + 1);
    PB();
    __builtin_amdgcn_s_setprio(1);
#pragma unroll
    for (int i = 0; i < 4; i++)
#pragma unroll
      for (int j = 0; j < 2; j++) ACCI(acc[0][i][j], afr[i], b0r[j]);
    __builtin_amdgcn_s_setprio(0);
    PB();

#pragma unroll
    for (int j = 0; j < 2; j++) b1r[j] = *(const i32x4*)&B1h[boff[j]];
    stage(0, gA, s + 2);
    stage(1, gB0, s + 2);
    PB();
    __builtin_amdgcn_s_setprio(1);
#pragma unroll
    for (int i = 0; i < 4; i++)
#pragma unroll
      for (int j = 0; j < 2; j++) ACCI(acc[1][i][j], afr[i], b1r[j]);
    __builtin_amdgcn_s_setprio(0);
    if (s >= NT - 2) { asm volatile("s_waitcnt vmcnt(0)" ::: "memory"); }
    else             { asm volatile("s_waitcnt vmcnt(2)" ::: "memory"); }
    __builtin_amdgcn_sched_barrier(0);
    __builtin_amdgcn_s_barrier();
    __builtin_amdgcn_sched_barrier(0);
  }

  // ---------------- epilogue (dequant) ----------------
#pragma unroll
  for (int i = 0; i < 4; i++) {
    int row = m0 + wm * 64 + i * 16 + lhi * 4;
    if (EPI == 0) {
      u16* out = (u16*)outp;
#pragma unroll
      for (int h = 0; h < 2; h++)
#pragma unroll
        for (int j = 0; j < 2; j++) {
          int colb = n0 + h * 128 + wn * 32 + j * 16;
          int col = colb + l15;
          int sh = colb >> 5;
          int d = (colb & 31) + l15;
          float bv = bias[col];
#pragma unroll
          for (int rg = 0; rg < 4; rg++)
            out[(size_t)sh * 2097152 + (size_t)(row + rg) * 32 + d] =
                f2bf((float)acc[h][i][j][rg] * INV_A + bv);
        }
    } else if (EPI == 1) {
      u16* sbw = (u16*)outp;
#pragma unroll
      for (int rg = 0; rg < 4; rg++) {
        int m = row + rg;
        int b = m >> 14, wi2 = (m >> 6) & 255, n = m & 63;
        int hh = (((wi2 >> 4) << 3) + (n >> 3) + 4) & 127;
        int w = (((wi2 & 15) << 3) + (n & 7) + 4) & 127;
        size_t pix = (((size_t)((b << 7) + hh) << 7) + (size_t)w) << 9;
#pragma unroll
        for (int h = 0; h < 2; h++)
#pragma unroll
          for (int j = 0; j < 2; j++) {
            int col = n0 + h * 128 + wn * 32 + j * 16 + l15;
            sbw[pix + col] = f2bf(resid[pix + col] +
                                  (float)acc[h][i][j][rg] * INV_P + bias[col]);
          }
      }
    } else if (EPI == 2) {
      float* out = (float*)outp;
      const u16* sbp = (const u16*)resid;
#pragma unroll
      for (int h = 0; h < 2; h++)
#pragma unroll
        for (int j = 0; j < 2; j++) {
          int col = n0 + h * 128 + wn * 32 + j * 16 + l15;
          float bv = bias[col];
#pragma unroll
          for (int rg = 0; rg < 4; rg++) {
            size_t idx = (size_t)(row + rg) * 512 + col;
            out[idx] = bf2f(sbp[idx]) + (float)acc[h][i][j][rg] * INV_H + bv;
          }
        }
    } else {
      char* out = (char*)outp;
#pragma unroll
      for (int j = 0; j < 2; j++) {
        int col = n0 + wn * 32 + j * 16 + l15;
        float ba_ = bias[col], bg_ = bias[col + 2048];
#pragma unroll
        for (int rg = 0; rg < 4; rg++) {
          float av = (float)acc[0][i][j][rg] * INV_A + ba_;
          float gv = (float)acc[1][i][j][rg] * INV_A + bg_;
          float sw = gv / (1.f + __expf(-gv));
          out[(size_t)(row + rg) * 2048 + col] = q8(sw * av, 64.f);
        }
      }
    }
  }
}

// ---------------- MFMA windowed attention (blocked bf16 qkv in, i8 out x32) -------
__global__ __launch_bounds__(256) void attn_mfma(
    const u16* __restrict__ qkv, char* __restrict__ out) {
  __shared__ __align__(16) char alds[4][15360];
  int tid = threadIdx.x;
  int wid = tid >> 6, lane = tid & 63;
  int bwin = blockIdx.x >> 2;
  int head = ((blockIdx.x & 3) << 2) + wid;
  int wi = bwin & 255;
  int wr = wi >> 4, wc = wi & 15;
  char* Wb = alds[wid];
  u16* Qr = (u16*)Wb;
  u16* Kr = (u16*)(Wb + 5120);
  u16* Vt = (u16*)(Wb + 10240);
  u16* PT = (u16*)Wb;
  int t = lane;
  int l15 = lane & 15, lhi = lane >> 4;
  size_t tok = (size_t)(bwin << 6) + t;
  const u16* qb = qkv + (size_t)head * 2097152 + tok * 32;
  union U { uint4 u; u16 s[8]; };
  U vq[4], vk[4], vv[4];
#pragma unroll
  for (int g = 0; g < 4; g++) {
    vq[g].u = *(const uint4*)(qb + (g << 3));
    vk[g].u = *(const uint4*)(qb + 33554432 + (g << 3));
    vv[g].u = *(const uint4*)(qb + 67108864 + (g << 3));
  }
  float q[32], k[32];
#pragma unroll
  for (int j = 0; j < 32; j++) {
    q[j] = bf2f(vq[j >> 3].s[j & 7]);
    k[j] = bf2f(vk[j >> 3].s[j & 7]);
  }
  int r = t >> 3, c = t & 7;
#pragma unroll
  for (int d = 0; d < 16; d++) {
    float pos = (d < 8) ? (float)r : (float)c;
    int dd = (d < 8) ? d : d - 8;
    float ang = pos * __expf(-(float)dd * 1.1512925465f);
    float sn, cs;
    __sincosf(ang, &sn, &cs);
    float q1 = q[d], q2 = q[d + 16];
    q[d] = q1 * cs - q2 * sn;  q[d + 16] = q2 * cs + q1 * sn;
    float k1 = k[d], k2 = k[d + 16];
    k[d] = k1 * cs - k2 * sn;  k[d + 16] = k2 * cs + k1 * sn;
  }
#pragma unroll
  for (int j = 0; j < 32; j++) q[j] *= 0.17677669529663687f;
#pragma unroll
  for (int sl = 0; sl < 4; sl++) {
    U tq, tk;
#pragma unroll
    for (int j = 0; j < 8; j++) { tq.s[j] = f2bf(q[sl * 8 + j]); tk.s[j] = f2bf(k[sl * 8 + j]); }
    *(uint4*)(Qr + t * 40 + sl * 8) = tq.u;
    *(uint4*)(Kr + t * 40 + sl * 8) = tk.u;
  }
#pragma unroll
  for (int j = 0; j < 32; j++) Vt[j * 72 + t] = vv[j >> 3].s[j & 7];
  bf16x8 kf[4], qf[4];
#pragma unroll
  for (int i = 0; i < 4; i++) {
    kf[i] = *(const bf16x8*)(Kr + (i * 16 + l15) * 40 + lhi * 8);
    qf[i] = *(const bf16x8*)(Qr + (i * 16 + l15) * 40 + lhi * 8);
  }
  f32x4 zz = {0.f, 0.f, 0.f, 0.f};
  f32x4 st[4][4];
#pragma unroll
  for (int mi = 0; mi < 4; mi++)
#pragma unroll
    for (int nj = 0; nj < 4; nj++)
      st[mi][nj] = __builtin_amdgcn_mfma_f32_16x16x32_bf16(kf[mi], qf[nj], zz, 0, 0, 0);
  if (wr == 15 || wc == 15) {
    int idh = (wr == 15) ? ((r >= 4) ? 2 : 1) : 0;
    int idw = (wc == 15) ? ((c >= 4) ? 2 : 1) : 0;
    int code = idh * 3 + idw;
    int cq[4], cm[4][4];
#pragma unroll
    for (int nj = 0; nj < 4; nj++) cq[nj] = __shfl(code, nj * 16 + l15);
#pragma unroll
    for (int mi = 0; mi < 4; mi++)
#pragma unroll
      for (int rg = 0; rg < 4; rg++) cm[mi][rg] = __shfl(code, mi * 16 + lhi * 4 + rg);
#pragma unroll
    for (int mi = 0; mi < 4; mi++)
#pragma unroll
      for (int nj = 0; nj < 4; nj++)
#pragma unroll
        for (int rg = 0; rg < 4; rg++)
          if (cm[mi][rg] != cq[nj]) st[mi][nj][rg] -= 100.f;
  }
  float inv_[4];
#pragma unroll
  for (int nj = 0; nj < 4; nj++) {
    float mx = -1e30f;
#pragma unroll
    for (int mi = 0; mi < 4; mi++)
#pragma unroll
      for (int rg = 0; rg < 4; rg++) mx = fmaxf(mx, st[mi][nj][rg]);
    mx = fmaxf(mx, __shfl_xor(mx, 16));
    mx = fmaxf(mx, __shfl_xor(mx, 32));
    float sum = 0.f;
#pragma unroll
    for (int mi = 0; mi < 4; mi++)
#pragma unroll
      for (int rg = 0; rg < 4; rg++) {
        float p = __expf(st[mi][nj][rg] - mx);
        st[mi][nj][rg] = p;
        sum += p;
      }
    sum += __shfl_xor(sum, 16);
    sum += __shfl_xor(sum, 32);
    inv_[nj] = 1.f / sum;
  }
#pragma unroll
  for (int mi = 0; mi < 4; mi++)
#pragma unroll
    for (int nj = 0; nj < 4; nj++) {
      uint32_t lo, hi;
      asm("v_cvt_pk_bf16_f32 %0, %1, %2" : "=v"(lo) : "v"(st[mi][nj][0]), "v"(st[mi][nj][1]));
      asm("v_cvt_pk_bf16_f32 %0, %1, %2" : "=v"(hi) : "v"(st[mi][nj][2]), "v"(st[mi][nj][3]));
      uint2 pr; pr.x = lo; pr.y = hi;
      *(uint2*)(PT + (nj * 16 + l15) * 72 + mi * 16 + lhi * 4) = pr;
    }
  bf16x8 vf[2][2], pf[4][2];
#pragma unroll
  for (int i = 0; i < 2; i++)
#pragma unroll
    for (int kc = 0; kc < 2; kc++)
      vf[i][kc] = *(const bf16x8*)(Vt + (i * 16 + l15) * 72 + kc * 32 + lhi * 8);
#pragma unroll
  for (int nj = 0; nj < 4; nj++)
#pragma unroll
    for (int kc = 0; kc < 2; kc++)
      pf[nj][kc] = *(const bf16x8*)(PT + (nj * 16 + l15) * 72 + kc * 32 + lhi * 8);
  char* Ot = Wb;
#pragma unroll
  for (int i = 0; i < 2; i++)
#pragma unroll
    for (int nj = 0; nj < 4; nj++) {
      f32x4 o = __builtin_amdgcn_mfma_f32_16x16x32_bf16(vf[i][0], pf[nj][0], zz, 0, 0, 0);
      o = __builtin_amdgcn_mfma_f32_16x16x32_bf16(vf[i][1], pf[nj][1], o, 0, 0, 0);
      float iv32 = inv_[nj] * 32.f;
      uint32_t pk = q8x4(o[0] * iv32, o[1] * iv32, o[2] * iv32, o[3] * iv32, 1.f);
      *(uint32_t*)(Ot + (nj * 16 + l15) * 40 + i * 16 + lhi * 4) = pk;
    }
#pragma unroll
  for (int g = 0; g < 4; g++) {
    int tl = g * 16 + (lane >> 2);
    int ch_ = (lane & 3) << 3;
    uint2 v = *(const uint2*)(Ot + tl * 40 + ch_);
    *(uint2*)(out + (size_t)((bwin << 6) + tl) * 512 + (head << 5) + ch_) = v;
  }
}

// ---------------- launch ----------------
extern "C" void kernel_launch(void* const* d_in, const int* in_sizes, int n_in,
                              void* d_out, int out_size, void* d_ws, size_t ws_size,
                              hipStream_t stream) {
  (void)in_sizes; (void)n_in; (void)out_size; (void)ws_size;
  const float* x      = (const float*)d_in[0];
  const float* n1g    = (const float*)d_in[2];
  const float* n1b    = (const float*)d_in[3];
  const float* qkv_w  = (const float*)d_in[4];
  const float* qkv_b  = (const float*)d_in[5];
  const float* proj_w = (const float*)d_in[6];
  const float* proj_b = (const float*)d_in[7];
  const float* n2g    = (const float*)d_in[8];
  const float* n2b    = (const float*)d_in[9];
  const float* fc1_w  = (const float*)d_in[10];
  const float* fc1_b  = (const float*)d_in[11];
  const float* fc2_w  = (const float*)d_in[12];
  const float* fc2_b  = (const float*)d_in[13];

  const size_t MB = 1048576ULL;
  char* ws = (char*)d_ws;
  char* wb8  = ws;                        // [0,4MB): qkv|proj|fc1|fc2 i8 weights
  char* wq8  = wb8;
  char* wp8  = wb8 + 786432;
  char* wf18 = wb8 + 1048576;
  char* wf28 = wb8 + 3145728;
  char* xw8  = ws + 8 * MB;               // [8,40): LN1 i8; later attn8
  char* attn8 = xw8;
  u16*  qkvb = (u16*)(ws + 72 * MB);      // [72,264): blocked bf16 qkv
  char* hb8  = ws + 8 * MB;               // [8,136): fc1 i8 h (qkv/attn dead)
  u16*  sb   = (u16*)(ws + 264 * MB);     // [264,328): bf16 residual s
  char* yb8  = ws + 328 * MB;             // [328,360): LN2 i8 out

  ln1_wconv<<<20480, 256, 0, stream>>>(x, n1g, n1b, xw8,
                                       qkv_w, proj_w, fc1_w, fc2_w, wb8);
  gemm2i<0, 512><<<3072, 512, 0, stream>>>(xw8, wq8, qkv_b, qkvb, nullptr, 6);
  attn_mfma<<<4096, 256, 0, stream>>>(qkvb, attn8);
  gemm2i<1, 512><<<1024, 512, 0, stream>>>(attn8, wp8, proj_b, sb, x, 2);
  ln2_q8<<<16384, 256, 0, stream>>>(sb, n2g, n2b, yb8);
  gemm2i<3, 512><<<8192, 512, 0, stream>>>(yb8, wf18, fc1_b, hb8, nullptr, 16);
  gemm2i<2, 2048><<<1024, 512, 0, stream>>>(hb8, wf28, fc2_b, d_out,
                                            (const float*)sb, 2);
}